// Round 10
// baseline (293.369 us; speedup 1.0000x reference)
//
#include <hip/hip_runtime.h>
#include <hip/hip_bf16.h>
#include <math.h>

// SGC: out = log_softmax( (A_norm^2 x) W^T + b )
// Restructure: (A^2 x) W^T == A^2 (x W^T) -> propagate 40-dim, not 512-dim.
// Weight factorization: store z' = dinv . z  (scaled in gemm epilogue), then
//   h1'[d] = dd^2 (z'[d] + sum_{s in N(d)} z'[s])        (pass 1, bf16)
//   logits[d] = dd (h1'[d] + sum h1'[s]) + b             (pass 2, fused lsm)
// -> spmm inner loop has NO per-edge weight: uniform s_load of csr indices,
//    40 lanes x global_load_ushort, v_add. Tail via dummy zero-row index N.
// CSR build: padded radix buckets + per-bucket counting sort (R9 structure).

#define NFEAT 512
#define NCLS  40
#define NBUCK_MAX 256          // buckets = ceil(N/512); N=100000 -> 196
#define CAP   18432            // bucket capacity: mean 16327 + 16 sigma

typedef __attribute__((ext_vector_type(8))) short bf16x8;
typedef __attribute__((ext_vector_type(4))) float f32x4;

__device__ inline short f2bf(float f) {
    union { float f; unsigned u; } v; v.f = f;
    unsigned r = (v.u + 0x7FFFu + ((v.u >> 16) & 1u)) >> 16;   // RNE
    return (short)r;
}
__device__ inline float bf2f(unsigned short u) {
    union { unsigned u; float f; } r; r.u = (unsigned)u << 16; return r.f;
}

// ---- 1. radix partition into padded buckets: bco[b*CAP + i] = (s<<9)|(d&511)

__global__ __launch_bounds__(256) void scat6_kernel(const int* __restrict__ src,
                                                    const int* __restrict__ dst,
                                                    int* __restrict__ bcursor,
                                                    unsigned* __restrict__ bco, int E) {
    __shared__ int h[NBUCK_MAX], h2[NBUCK_MAX], base[NBUCK_MAX];
    int t = threadIdx.x;
    h[t] = 0; h2[t] = 0;
    __syncthreads();
    int cb = blockIdx.x * 2048;
    int d[8], s[8];
    bool m[8];
    #pragma unroll
    for (int u = 0; u < 8; ++u) {
        int e = cb + u * 256 + t;
        m[u] = e < E;
        d[u] = m[u] ? __builtin_nontemporal_load(dst + e) : 0;
        s[u] = m[u] ? __builtin_nontemporal_load(src + e) : 0;
        if (m[u]) atomicAdd(&h[d[u] >> 9], 1);
    }
    __syncthreads();
    if (h[t]) base[t] = t * CAP + atomicAdd(&bcursor[t], h[t]);
    __syncthreads();
    #pragma unroll
    for (int u = 0; u < 8; ++u) {
        if (m[u]) {
            int b = d[u] >> 9;
            int lp = atomicAdd(&h2[b], 1);
            bco[base[b] + lp] = ((unsigned)s[u] << 9) | (unsigned)(d[u] & 511);
        }
    }
}

// ---- 2. per-bucket counting sort -> rowinfo{beg,cnt,dinv}, dinv, csr_src --

__global__ __launch_bounds__(256) void sortb2_kernel(const unsigned* __restrict__ bco,
                                                     const int* __restrict__ bcursor,
                                                     int4* __restrict__ rowinfo,
                                                     float* __restrict__ dinv,
                                                     int* __restrict__ csr_src, int N) {
    __shared__ int deg[512], ex[512], sc[256];
    int b = blockIdx.x, t = threadIdx.x;
    int lo = b * 512;
    int nn = N - lo; if (nn > 512) nn = 512;
    int ebeg = b * CAP;
    int ecnt = bcursor[b];

    deg[t] = 0; deg[t + 256] = 0;
    __syncthreads();
    for (int i = t; i < ecnt; i += 256)
        atomicAdd(&deg[bco[ebeg + i] & 511u], 1);
    __syncthreads();
    int a0 = deg[2 * t], a1 = deg[2 * t + 1];
    int ps = a0 + a1;
    sc[t] = ps;
    __syncthreads();
    for (int off = 1; off < 256; off <<= 1) {
        int u = (t >= off) ? sc[t - off] : 0;
        __syncthreads();
        sc[t] += u;
        __syncthreads();
    }
    int pb = sc[t] - ps;
    ex[2 * t] = pb; ex[2 * t + 1] = pb + a0;
    __syncthreads();
    for (int j = t; j < nn; j += 256) {
        float di = rsqrtf((float)(deg[j] + 1));      // +1 self-loop
        int4 ri;
        ri.x = ebeg + ex[j];
        ri.y = deg[j];
        ri.z = __float_as_int(di);
        ri.w = 0;
        rowinfo[lo + j] = ri;
        dinv[lo + j]    = di;
    }
    __syncthreads();
    for (int i = t; i < ecnt; i += 256) {
        unsigned v = bco[ebeg + i];
        int p = atomicAdd(&ex[v & 511u], 1);
        csr_src[ebeg + p] = (int)(v >> 9);
    }
}

// ---- W -> MFMA fragment pack; also zero the dummy row N of zb/h1 ---------
// slot map (same on A side): k = kc*32 + (lane>>4)*8 + j, col = tile*16+(lane&15)

__global__ void wfrag_kernel(const float* __restrict__ W, short* __restrict__ wfrag,
                             unsigned short* __restrict__ zb,
                             unsigned short* __restrict__ h1, int N) {
    int i = blockIdx.x * blockDim.x + threadIdx.x;
    if (blockIdx.x == 0 && threadIdx.x < NCLS) {
        zb[(size_t)N * NCLS + threadIdx.x] = 0;
        h1[(size_t)N * NCLS + threadIdx.x] = 0;
    }
    if (i >= 16 * 3 * 64) return;
    int kc = i / 192, rem = i % 192, tile = rem / 64, lane = rem % 64;
    int c = tile * 16 + (lane & 15);
    int kbase = kc * 32 + ((lane >> 4) << 3);
    bf16x8 out;
    #pragma unroll
    for (int j = 0; j < 8; ++j) {
        float v = (c < NCLS) ? W[(size_t)c * NFEAT + kbase + j] : 0.f;
        out[j] = f2bf(v);
    }
    *(bf16x8*)(wfrag + (size_t)i * 8) = out;
}

// ---- z' = dinv . (x @ W^T) via MFMA bf16, double-buffered LDS ------------

__global__ __launch_bounds__(512) void gemm5_kernel(const float* __restrict__ x,
                                                    const short* __restrict__ wfrag,
                                                    const float* __restrict__ dinv,
                                                    unsigned short* __restrict__ zb, int n) {
    __shared__ short xl[2][128 * 40];
    int t = threadIdx.x;
    int w = t >> 6, l = t & 63;
    int lrow = l & 15, lk = l >> 4;
    int rowBase = blockIdx.x * 128;
    int srow = t >> 2, skq = t & 3;
    f32x4 acc0 = {0.f, 0.f, 0.f, 0.f}, acc1 = acc0, acc2 = acc0;
    const float* xrow = x + (size_t)(rowBase + srow) * NFEAT + skq * 8;
    bool srOK = (rowBase + srow) < n;
    int aoff = (w * 16 + lrow) * 40 + lk * 8;
    int doff = srow * 40 + skq * 8;

    {   // prologue: stage kc=0
        float4 v0 = make_float4(0.f, 0.f, 0.f, 0.f), v1 = v0;
        if (srOK) { const float4* xp = (const float4*)xrow; v0 = xp[0]; v1 = xp[1]; }
        bf16x8 bv;
        bv[0] = f2bf(v0.x); bv[1] = f2bf(v0.y); bv[2] = f2bf(v0.z); bv[3] = f2bf(v0.w);
        bv[4] = f2bf(v1.x); bv[5] = f2bf(v1.y); bv[6] = f2bf(v1.z); bv[7] = f2bf(v1.w);
        *(bf16x8*)&xl[0][doff] = bv;
    }
    __syncthreads();

    for (int kc = 0; kc < 16; ++kc) {
        int cur = kc & 1;
        float4 v0 = make_float4(0.f, 0.f, 0.f, 0.f), v1 = v0;
        if (kc < 15 && srOK) {                      // issue next chunk early
            const float4* xp = (const float4*)(xrow + (kc + 1) * 32);
            v0 = xp[0]; v1 = xp[1];
        }
        bf16x8 af = *(const bf16x8*)&xl[cur][aoff];
        const bf16x8* wf = (const bf16x8*)(wfrag + (size_t)kc * 3 * 64 * 8);
        bf16x8 b0 = wf[l];
        bf16x8 b1 = wf[64 + l];
        bf16x8 b2 = wf[128 + l];
        acc0 = __builtin_amdgcn_mfma_f32_16x16x32_bf16(af, b0, acc0, 0, 0, 0);
        acc1 = __builtin_amdgcn_mfma_f32_16x16x32_bf16(af, b1, acc1, 0, 0, 0);
        acc2 = __builtin_amdgcn_mfma_f32_16x16x32_bf16(af, b2, acc2, 0, 0, 0);
        if (kc < 15) {
            bf16x8 bv;
            bv[0] = f2bf(v0.x); bv[1] = f2bf(v0.y); bv[2] = f2bf(v0.z); bv[3] = f2bf(v0.w);
            bv[4] = f2bf(v1.x); bv[5] = f2bf(v1.y); bv[6] = f2bf(v1.z); bv[7] = f2bf(v1.w);
            *(bf16x8*)&xl[cur ^ 1][doff] = bv;
            __syncthreads();
        }
    }
    int r0 = rowBase + w * 16 + lk * 4;    // C/D: col=lane&15, row=(lane>>4)*4+reg
    #pragma unroll
    for (int reg = 0; reg < 4; ++reg) {
        int row = r0 + reg;
        if (row < n) {
            float sc = dinv[row];                   // pre-scale: z' = dinv*z
            unsigned short* zp = zb + (size_t)row * NCLS;
            zp[lrow]      = (unsigned short)f2bf(acc0[reg] * sc);
            zp[16 + lrow] = (unsigned short)f2bf(acc1[reg] * sc);
            if (lrow < 8) zp[32 + lrow] = (unsigned short)f2bf(acc2[reg] * sc);
        }
    }
}

// ---- unweighted pull-SpMM: wave per dst, scalar-uniform edge loop --------
// sum = in'[d] + sum_s in'[s]; pass1 out = dd^2*sum (bf16); final:
// logits = dd*sum + bias -> log_softmax -> float out.

template <bool FINAL>
__global__ __launch_bounds__(256) void spmm5_kernel(const unsigned short* __restrict__ in,
                                                    const int4* __restrict__ rowinfo,
                                                    const int* __restrict__ csr,
                                                    const float* __restrict__ bias,
                                                    void* __restrict__ outv, int n) {
    int wv = (int)((blockIdx.x * (size_t)blockDim.x + threadIdx.x) >> 6);
    wv = __builtin_amdgcn_readfirstlane(wv);        // force SGPR (uniform)
    if (wv >= n) return;
    int lane = threadIdx.x & 63;

    int4 ri = rowinfo[wv];                          // s_load_dwordx4
    int beg = ri.x, tot = ri.y;
    float dd = __int_as_float(ri.z);

    // self term (lanes >=40 read pad garbage, discarded)
    float a = bf2f(in[(size_t)wv * NCLS + lane]);

    int j = 0;
    for (; j + 4 <= tot; j += 4) {
        int s0 = csr[beg + j];
        int s1 = csr[beg + j + 1];
        int s2 = csr[beg + j + 2];
        int s3 = csr[beg + j + 3];
        float v0 = bf2f(in[(size_t)s0 * NCLS + lane]);
        float v1 = bf2f(in[(size_t)s1 * NCLS + lane]);
        float v2 = bf2f(in[(size_t)s2 * NCLS + lane]);
        float v3 = bf2f(in[(size_t)s3 * NCLS + lane]);
        a += v0; a += v1; a += v2; a += v3;
    }
    for (; j < tot; ++j) {
        int s = csr[beg + j];
        a += bf2f(in[(size_t)s * NCLS + lane]);
    }

    if (!FINAL) {
        if (lane < NCLS) {
            unsigned short* ob = (unsigned short*)outv;
            ob[(size_t)wv * NCLS + lane] = (unsigned short)f2bf(a * dd * dd);
        }
    } else {
        float v = (lane < NCLS) ? a * dd + bias[lane] : -INFINITY;
        float m = v;
        #pragma unroll
        for (int off = 32; off; off >>= 1) m = fmaxf(m, __shfl_xor(m, off, 64));
        float e = (lane < NCLS) ? expf(v - m) : 0.f;
        float s = e;
        #pragma unroll
        for (int off = 32; off; off >>= 1) s += __shfl_xor(s, off, 64);
        float lse = logf(s);
        if (lane < NCLS) {
            float* out = (float*)outv;
            out[(size_t)wv * NCLS + lane] = v - m - lse;
        }
    }
}

// ---- driver -------------------------------------------------------------

extern "C" void kernel_launch(void* const* d_in, const int* in_sizes, int n_in,
                              void* d_out, int out_size, void* d_ws, size_t ws_size,
                              hipStream_t stream) {
    const float* x  = (const float*)d_in[0];
    const int*   ei = (const int*)d_in[1];
    const float* W  = (const float*)d_in[2];
    const float* b  = (const float*)d_in[3];

    const int N = in_sizes[0] / NFEAT;
    const int E = in_sizes[1] / 2;
    const int* src = ei;
    const int* dst = ei + E;
    const int nbuck = (N + 511) / 512;     // 196

    char* p = (char*)d_ws;
    auto alloc = [&](size_t bytes) -> void* {
        void* r = (void*)p;
        p += (bytes + 255) & ~(size_t)255;
        return r;
    };
    int*      bcursor = (int*)     alloc((size_t)NBUCK_MAX * 4);
    int4*     rowinfo = (int4*)    alloc((size_t)N * 16);
    float*    dinv    = (float*)   alloc((size_t)N * 4);
    unsigned* bco     = (unsigned*)alloc((size_t)nbuck * CAP * 4 + 64);
    int*      csr_src = (int*)     alloc((size_t)nbuck * CAP * 4 + 64);
    short*    wfrag   = (short*)   alloc((size_t)16 * 3 * 64 * 8 * 2);
    unsigned short* zb = (unsigned short*)alloc(((size_t)N + 1) * NCLS * 2 + 256);
    unsigned short* h1 = (unsigned short*)alloc(((size_t)N + 1) * NCLS * 2 + 256);

    hipMemsetAsync(bcursor, 0, (size_t)NBUCK_MAX * 4, stream);

    int cb = (E + 2047) / 2048;
    scat6_kernel<<<cb, 256, 0, stream>>>(src, dst, bcursor, bco, E);
    sortb2_kernel<<<nbuck, 256, 0, stream>>>(bco, bcursor, rowinfo, dinv, csr_src, N);

    wfrag_kernel<<<12, 256, 0, stream>>>(W, wfrag, zb, h1, N);
    gemm5_kernel<<<(N + 127) / 128, 512, 0, stream>>>(x, wfrag, dinv, zb, N);

    int wb = (int)(((size_t)N * 64 + 255) / 256);
    spmm5_kernel<false><<<wb, 256, 0, stream>>>(zb, rowinfo, csr_src, b, h1, N);
    spmm5_kernel<true ><<<wb, 256, 0, stream>>>(h1, rowinfo, csr_src, b, d_out, N);
}